// Round 14
// baseline (3571.492 us; speedup 1.0000x reference)
//
#include <hip/hip_runtime.h>
#include <hip/hip_bf16.h>

#define DEPTHL 8
#define BZ 8
#define SEQ 1024
#define CDIM 768
#define HEADS 12
#define HDIM 64
#define MLPD 3072
#define TOK (BZ*SEQ)      // 8192
#define QKVN (3*CDIM)     // 2304

typedef __attribute__((ext_vector_type(8))) short vshort8;
typedef __attribute__((ext_vector_type(4))) short vshort4;
typedef __attribute__((ext_vector_type(4))) float vfloat4;

__device__ __forceinline__ short bf16_bits(float f) {
  union { float f; unsigned u; } x; x.f = f;
  unsigned r = (x.u + 0x7FFFu + ((x.u >> 16) & 1u)) >> 16;
  return (short)r;
}

__device__ __forceinline__ unsigned pk_bf16(float a, float b) {
  unsigned r;
  asm("v_cvt_pk_bf16_f32 %0, %1, %2" : "=v"(r) : "v"(a), "v"(b));
  return r;   // low16 = bf16(a), high16 = bf16(b)
}

#define GL16(g, l) __builtin_amdgcn_global_load_lds( \
    (const __attribute__((address_space(1))) unsigned int*)(g), \
    (__attribute__((address_space(3))) unsigned int*)(l), 16, 0, 0)

// ---------------- weight convert + transpose: fp32 [D][K][N] -> bf16 [D][N][K]
__global__ __launch_bounds__(256) void wconv_t(const float* __restrict__ in,
                                               short* __restrict__ out,
                                               int K, int N) {
  __shared__ float tile[32][33];
  const long d = blockIdx.z;
  in  += d * (long)K * N;
  out += d * (long)N * K;
  const int n0 = blockIdx.x * 32, k0 = blockIdx.y * 32;
  const int tx = threadIdx.x & 31, ty = threadIdx.x >> 5;
#pragma unroll
  for (int i = 0; i < 4; i++)
    tile[ty + 8*i][tx] = in[(long)(k0 + ty + 8*i) * N + n0 + tx];
  __syncthreads();
#pragma unroll
  for (int i = 0; i < 4; i++)
    out[(long)(n0 + ty + 8*i) * K + k0 + tx] = bf16_bits(tile[tx][ty + 8*i]);
}

// ---------------- LayerNorm: 1 wave per row, 4 rows per block, shfl-only
__global__ __launch_bounds__(256) void ln_fwd(const float* __restrict__ h,
                                              const float* __restrict__ g,
                                              const float* __restrict__ be,
                                              short* __restrict__ y) {
  const int row = blockIdx.x * 4 + (threadIdx.x >> 6);
  const int lane = threadIdx.x & 63;
  const float4* hr = (const float4*)(h + (long)row * CDIM);
  const float4 v0 = hr[lane], v1 = hr[lane + 64], v2 = hr[lane + 128];
  float s = (v0.x + v0.y + v0.z + v0.w) + (v1.x + v1.y + v1.z + v1.w)
          + (v2.x + v2.y + v2.z + v2.w);
#pragma unroll
  for (int m = 32; m >= 1; m >>= 1) s += __shfl_xor(s, m);
  const float mu = s * (1.0f / CDIM);
  float d0x = v0.x - mu, d0y = v0.y - mu, d0z = v0.z - mu, d0w = v0.w - mu;
  float d1x = v1.x - mu, d1y = v1.y - mu, d1z = v1.z - mu, d1w = v1.w - mu;
  float d2x = v2.x - mu, d2y = v2.y - mu, d2z = v2.z - mu, d2w = v2.w - mu;
  float q = (d0x*d0x + d0y*d0y + d0z*d0z + d0w*d0w)
          + (d1x*d1x + d1y*d1y + d1z*d1z + d1w*d1w)
          + (d2x*d2x + d2y*d2y + d2z*d2z + d2w*d2w);
#pragma unroll
  for (int m = 32; m >= 1; m >>= 1) q += __shfl_xor(q, m);
  const float rstd = rsqrtf(q * (1.0f / CDIM) + 1e-5f);
  const float4* gp = (const float4*)g;
  const float4* bp = (const float4*)be;
  short* yr = y + (long)row * CDIM;
#pragma unroll
  for (int c = 0; c < 3; c++) {
    const float4 g4 = gp[lane + c * 64];
    const float4 b4 = bp[lane + c * 64];
    float dx = (c == 0 ? d0x : c == 1 ? d1x : d2x);
    float dy = (c == 0 ? d0y : c == 1 ? d1y : d2y);
    float dz = (c == 0 ? d0z : c == 1 ? d1z : d2z);
    float dw = (c == 0 ? d0w : c == 1 ? d1w : d2w);
    vshort4 o;
    o[0] = bf16_bits(dx * rstd * g4.x + b4.x);
    o[1] = bf16_bits(dy * rstd * g4.y + b4.y);
    o[2] = bf16_bits(dz * rstd * g4.z + b4.z);
    o[3] = bf16_bits(dw * rstd * g4.w + b4.w);
    *(vshort4*)(yr + c * 256 + lane * 4) = o;
  }
}

// ---------------- GEMM: 128x128 tile, BK=64 (R9 config). EPI: 0 bf16 store,
// 1 bias+relu, 2 bias+residual fp32, 3 = bf16 store + fused V-transpose scatter
template<int EPI>
__global__ __launch_bounds__(256) void gemm_bt(const short* __restrict__ A,
                                               const short* __restrict__ Bt,
                                               const float* __restrict__ bias,
                                               void* __restrict__ Cout,
                                               short* __restrict__ vt2,
                                               int M, int N, int K) {
  __shared__ short As[128 * 64];
  __shared__ short Bs[128 * 64];
  const int tid = threadIdx.x;
  const int wid = tid >> 6, lane = tid & 63;
  const int lg = lane >> 4, lr = lane & 15;
  const int wm = wid >> 1, wn = wid & 1;

  const int gx = gridDim.x;
  const int nwg = gx * gridDim.y;
  int flat = blockIdx.y * gx + blockIdx.x;
  flat = (flat & 7) * (nwg >> 3) + (flat >> 3);   // same-XCD blocks contiguous
  const long bx = flat % gx;
  const long by = flat / gx;

  vfloat4 acc[4][4];
#pragma unroll
  for (int i = 0; i < 4; i++)
#pragma unroll
    for (int j = 0; j < 4; j++) acc[i][j] = (vfloat4){0.f, 0.f, 0.f, 0.f};

  const short* Abase = A  + by * 128 * (long)K;
  const short* Bbase = Bt + bx * 128 * (long)K;

  for (int kk = 0; kk < K; kk += 64) {
    __syncthreads();
#pragma unroll
    for (int ch = 0; ch < 4; ch++) {
      const int dst = tid * 16 + ch * 4096;
      const int off = dst ^ (((dst >> 7) & 7) << 4);
      const long srow = off >> 7;
      const int scol = (off & 127) >> 1;
      GL16(Abase + srow * K + kk + scol, As + (dst >> 1));
      GL16(Bbase + srow * K + kk + scol, Bs + (dst >> 1));
    }
    __syncthreads();
#pragma unroll
    for (int kh = 0; kh < 2; kh++) {
      vshort8 a[4], b[4];
#pragma unroll
      for (int mt = 0; mt < 4; mt++) {
        const int row = wm * 64 + mt * 16 + lr;
        int byt = row * 128 + kh * 64 + lg * 16;
        byt ^= (row & 7) << 4;
        a[mt] = *(const vshort8*)((const char*)As + byt);
      }
#pragma unroll
      for (int nt = 0; nt < 4; nt++) {
        const int row = wn * 64 + nt * 16 + lr;
        int byt = row * 128 + kh * 64 + lg * 16;
        byt ^= (row & 7) << 4;
        b[nt] = *(const vshort8*)((const char*)Bs + byt);
      }
#pragma unroll
      for (int mt = 0; mt < 4; mt++)
#pragma unroll
        for (int nt = 0; nt < 4; nt++)
          acc[mt][nt] = __builtin_amdgcn_mfma_f32_16x16x32_bf16(a[mt], b[nt], acc[mt][nt], 0, 0, 0);
    }
  }

  const long row0 = by * 128 + wm * 64;
  const long col0 = bx * 128 + wn * 64;
#pragma unroll
  for (int mt = 0; mt < 4; mt++) {
#pragma unroll
    for (int nt = 0; nt < 4; nt++) {
      const long col = col0 + nt * 16 + lr;
      float bv = 0.f;
      if (EPI == 1 || EPI == 2) bv = bias[col];
#pragma unroll
      for (int r = 0; r < 4; r++) {
        const long row = row0 + mt * 16 + lg * 4 + r;
        float v = acc[mt][nt][r];
        if (EPI == 0) {
          ((short*)Cout)[row * N + col] = bf16_bits(v);
        } else if (EPI == 1) {
          v += bv; v = v > 0.f ? v : 0.f;
          ((short*)Cout)[row * N + col] = bf16_bits(v);
        } else if (EPI == 2) {
          float* hp = (float*)Cout + row * N + col;
          *hp = *hp + v + bv;
        } else {
          const short bb = bf16_bits(v);
          ((short*)Cout)[row * N + col] = bb;
          if (col >= 2 * CDIM) {            // V part: also write vt[bh][d][tok]
            const int dg = (int)col - 2 * CDIM;
            const int hh2 = dg >> 6, dd = dg & 63;
            const long bidx = row >> 10, tok = row & 1023;
            vt2[(((bidx * HEADS + hh2) << 6) + dd) * (long)SEQ + tok] = bb;
          }
        }
      }
    }
  }
}

// ---------------- GEMM 256x128 (M x N), BK=64, 512 thr / 8 waves.
// For FC1: grid 24x32 = 768 blocks = exactly 3/CU (LDS 48KB) -> one full round.
// 2x MFMA per barrier-pair vs 128^2 (m233 stall amortization).
template<int EPI>
__global__ __launch_bounds__(512) void gemm_mk(const short* __restrict__ A,
                                               const short* __restrict__ Bt,
                                               const float* __restrict__ bias,
                                               void* __restrict__ Cout,
                                               int M, int N, int K) {
  __shared__ short As[256 * 64];   // 32KB
  __shared__ short Bs[128 * 64];   // 16KB
  const int tid = threadIdx.x;
  const int wid = tid >> 6, lane = tid & 63;
  const int lg = lane >> 4, lr = lane & 15;

  const int gx = gridDim.x;
  const int nwg = gx * gridDim.y;
  int flat = blockIdx.y * gx + blockIdx.x;
  flat = (flat & 7) * (nwg >> 3) + (flat >> 3);
  const long bx = flat % gx;
  const long by = flat / gx;

  vfloat4 acc[2][8];
#pragma unroll
  for (int i = 0; i < 2; i++)
#pragma unroll
    for (int j = 0; j < 8; j++) acc[i][j] = (vfloat4){0.f, 0.f, 0.f, 0.f};

  const short* Abase = A  + by * 256 * (long)K;
  const short* Bbase = Bt + bx * 128 * (long)K;

  for (int kk = 0; kk < K; kk += 64) {
    __syncthreads();
#pragma unroll
    for (int ch = 0; ch < 4; ch++) {       // A: 32KB
      const int dst = tid * 16 + ch * 8192;
      const int off = dst ^ (((dst >> 7) & 7) << 4);
      const long srow = off >> 7;
      const int scol = (off & 127) >> 1;
      GL16(Abase + srow * K + kk + scol, As + (dst >> 1));
    }
#pragma unroll
    for (int ch = 0; ch < 2; ch++) {       // B: 16KB
      const int dst = tid * 16 + ch * 8192;
      const int off = dst ^ (((dst >> 7) & 7) << 4);
      const long srow = off >> 7;
      const int scol = (off & 127) >> 1;
      GL16(Bbase + srow * K + kk + scol, Bs + (dst >> 1));
    }
    __syncthreads();
#pragma unroll
    for (int kh = 0; kh < 2; kh++) {
      vshort8 a[2], b[8];
#pragma unroll
      for (int mt = 0; mt < 2; mt++) {
        const int row = wid * 32 + mt * 16 + lr;
        int byt = row * 128 + kh * 64 + lg * 16;
        byt ^= (row & 7) << 4;
        a[mt] = *(const vshort8*)((const char*)As + byt);
      }
#pragma unroll
      for (int nt = 0; nt < 8; nt++) {
        const int row = nt * 16 + lr;
        int byt = row * 128 + kh * 64 + lg * 16;
        byt ^= (row & 7) << 4;
        b[nt] = *(const vshort8*)((const char*)Bs + byt);
      }
#pragma unroll
      for (int mt = 0; mt < 2; mt++)
#pragma unroll
        for (int nt = 0; nt < 8; nt++)
          acc[mt][nt] = __builtin_amdgcn_mfma_f32_16x16x32_bf16(a[mt], b[nt], acc[mt][nt], 0, 0, 0);
    }
  }

  const long row0 = by * 256 + wid * 32;
  const long col0 = bx * 128;
#pragma unroll
  for (int mt = 0; mt < 2; mt++) {
#pragma unroll
    for (int nt = 0; nt < 8; nt++) {
      const long col = col0 + nt * 16 + lr;
      float bv = 0.f;
      if (EPI != 0) bv = bias[col];
#pragma unroll
      for (int r = 0; r < 4; r++) {
        const long row = row0 + mt * 16 + lg * 4 + r;
        float v = acc[mt][nt][r];
        if (EPI == 0) {
          ((short*)Cout)[row * N + col] = bf16_bits(v);
        } else if (EPI == 1) {
          v += bv; v = v > 0.f ? v : 0.f;
          ((short*)Cout)[row * N + col] = bf16_bits(v);
        } else {
          float* hp = (float*)Cout + row * N + col;
          *hp = *hp + v + bv;
        }
      }
    }
  }
}

// ---------------- fused attention v6 (R13 best: 185us/dispatch)
__global__ __launch_bounds__(256) void attn_fused6(const short* __restrict__ qkv,
                                                   const short* __restrict__ vt,
                                                   short* __restrict__ o) {
  __shared__ __align__(16) short P_lds[4 * 2 * 4096];   // [wave][half][16q x 256kv]
  __shared__ float redm[4][16], redz[4][16], redt[4][16];
  int flat = blockIdx.y * 32 + blockIdx.x;          // nwg = 3072
  flat = (flat & 7) * (3072 >> 3) + (flat >> 3);    // 384/XCD = 12 heads
  const int qt = flat & 31;
  const int bh = flat >> 5;
  const int b = bh / HEADS, hh = bh % HEADS;
  const int tid = threadIdx.x, wid = tid >> 6, lane = tid & 63;
  const int lg = lane >> 4, lr = lane & 15;
  const long tokbase = (long)b * SEQ;
  const short* qbase = qkv + tokbase * QKVN + hh * HDIM;
  const short* kbase = qkv + tokbase * QKVN + CDIM + hh * HDIM;
  const short* vtb = vt + (long)bh * HDIM * SEQ;
  char* Pw0 = (char*)P_lds + wid * 16384;
  char* Pw1 = Pw0 + 8192;

  vshort8 qf0[2], qf1[2];
#pragma unroll
  for (int ks = 0; ks < 2; ks++) {
    qf0[ks] = *(const vshort8*)(qbase + (long)(qt * 32 + lr) * QKVN + ks * 32 + lg * 8);
    qf1[ks] = *(const vshort8*)(qbase + (long)(qt * 32 + 16 + lr) * QKVN + ks * 32 + lg * 8);
  }

  vfloat4 s0[16], s1[16];
#pragma unroll
  for (int bb = 0; bb < 4; bb++) {
    vshort8 kf[8];
#pragma unroll
    for (int u = 0; u < 4; u++) {
      const int n0 = wid * 256 + (bb * 4 + u) * 16;
#pragma unroll
      for (int ks = 0; ks < 2; ks++)
        kf[u * 2 + ks] = *(const vshort8*)(kbase + (long)(n0 + lr) * QKVN + ks * 32 + lg * 8);
    }
#pragma unroll
    for (int u = 0; u < 4; u++) {
      vfloat4 a0 = (vfloat4){0.f, 0.f, 0.f, 0.f};
      a0 = __builtin_amdgcn_mfma_f32_16x16x32_bf16(kf[u * 2 + 0], qf0[0], a0, 0, 0, 0);
      a0 = __builtin_amdgcn_mfma_f32_16x16x32_bf16(kf[u * 2 + 1], qf0[1], a0, 0, 0, 0);
      s0[bb * 4 + u] = a0;
      vfloat4 a1 = (vfloat4){0.f, 0.f, 0.f, 0.f};
      a1 = __builtin_amdgcn_mfma_f32_16x16x32_bf16(kf[u * 2 + 0], qf1[0], a1, 0, 0, 0);
      a1 = __builtin_amdgcn_mfma_f32_16x16x32_bf16(kf[u * 2 + 1], qf1[1], a1, 0, 0, 0);
      s1[bb * 4 + u] = a1;
    }
  }

  float rt0, rt1;
#define SOFTMAX_HALF(S, RT)                                                   \
  {                                                                           \
    float mt16[16];                                                           \
    _Pragma("unroll")                                                         \
    for (int i = 0; i < 16; i++)                                              \
      mt16[i] = fmaxf(fmaxf(S[i][0], S[i][1]), fmaxf(S[i][2], S[i][3]));      \
    _Pragma("unroll")                                                         \
    for (int st = 8; st >= 1; st >>= 1)                                       \
      _Pragma("unroll")                                                       \
      for (int i = 0; i < 8; i++) if (i < st) mt16[i] = fmaxf(mt16[i], mt16[i + st]); \
    float m = mt16[0];                                                        \
    m = fmaxf(m, __shfl_xor(m, 16));                                          \
    m = fmaxf(m, __shfl_xor(m, 32));                                          \
    if (lane < 16) redm[wid][lr] = m;                                         \
    __syncthreads();                                                          \
    m = fmaxf(fmaxf(redm[0][lr], redm[1][lr]), fmaxf(redm[2][lr], redm[3][lr])); \
    const float msc = m * 0.125f;                                             \
    float zt[16];                                                             \
    _Pragma("unroll")                                                         \
    for (int i = 0; i < 16; i++) {                                            \
      float e0 = __expf(fmaf(S[i][0], 0.125f, -msc));                         \
      float e1 = __expf(fmaf(S[i][1], 0.125f, -msc));                         \
      float e2 = __expf(fmaf(S[i][2], 0.125f, -msc));                         \
      float e3 = __expf(fmaf(S[i][3], 0.125f, -msc));                         \
      S[i][0] = e0; S[i][1] = e1; S[i][2] = e2; S[i][3] = e3;                 \
      zt[i] = (e0 + e1) + (e2 + e3);                                          \
    }                                                                         \
    _Pragma("unroll")                                                         \
    for (int st = 8; st >= 1; st >>= 1)                                       \
      _Pragma("unroll")                                                       \
      for (int i = 0; i < 8; i++) if (i < st) zt[i] += zt[i + st];            \
    float z = zt[0];                                                          \
    z += __shfl_xor(z, 16);                                                   \
    z += __shfl_xor(z, 32);                                                   \
    if (lane < 16) redz[wid][lr] = z;                                         \
    __syncthreads();                                                          \
    z = (redz[0][lr] + redz[1][lr]) + (redz[2][lr] + redz[3][lr]);            \
    const float rz = 1.0f / z;                                                \
    float tt[16];                                                             \
    _Pragma("unroll")                                                         \
    for (int i = 0; i < 16; i++) {                                            \
      float p0 = __expf(S[i][0] * rz);                                        \
      float p1 = __expf(S[i][1] * rz);                                        \
      float p2 = __expf(S[i][2] * rz);                                        \
      float p3 = __expf(S[i][3] * rz);                                        \
      S[i][0] = p0; S[i][1] = p1; S[i][2] = p2; S[i][3] = p3;                 \
      tt[i] = (p0 + p1) + (p2 + p3);                                          \
    }                                                                         \
    _Pragma("unroll")                                                         \
    for (int st = 8; st >= 1; st >>= 1)                                       \
      _Pragma("unroll")                                                       \
      for (int i = 0; i < 8; i++) if (i < st) tt[i] += tt[i + st];            \
    float t2 = tt[0];                                                         \
    t2 += __shfl_xor(t2, 16);                                                 \
    t2 += __shfl_xor(t2, 32);                                                 \
    if (lane < 16) redt[wid][lr] = t2;                                        \
    __syncthreads();                                                          \
    t2 = (redt[0][lr] + redt[1][lr]) + (redt[2][lr] + redt[3][lr]);           \
    RT = 1.0f / t2;                                                           \
  }

  SOFTMAX_HALF(s0, rt0)
  SOFTMAX_HALF(s1, rt1)
#undef SOFTMAX_HALF

#pragma unroll
  for (int i = 0; i < 16; i++) {
    const int byt = (lr * 512 + i * 32 + lg * 8) ^ ((lr & 7) << 4);
    uint2 pk0, pk1;
    pk0.x = pk_bf16(s0[i][0] * rt0, s0[i][1] * rt0);
    pk0.y = pk_bf16(s0[i][2] * rt0, s0[i][3] * rt0);
    pk1.x = pk_bf16(s1[i][0] * rt1, s1[i][1] * rt1);
    pk1.y = pk_bf16(s1[i][2] * rt1, s1[i][3] * rt1);
    *(uint2*)(Pw0 + byt) = pk0;
    *(uint2*)(Pw1 + byt) = pk1;
  }

  vfloat4 o0[4], o1[4];
#pragma unroll
  for (int dt = 0; dt < 4; dt++) {
    o0[dt] = (vfloat4){0.f, 0.f, 0.f, 0.f};
    o1[dt] = (vfloat4){0.f, 0.f, 0.f, 0.f};
  }
#pragma unroll
  for (int j = 0; j < 8; j++) {
    const int abyt = (lr * 512 + j * 64 + lg * 16) ^ ((lr & 7) << 4);
    vshort8 af0 = *(const vshort8*)(Pw0 + abyt);
    vshort8 af1 = *(const vshort8*)(Pw1 + abyt);
#pragma unroll
    for (int dt = 0; dt < 4; dt++) {
      vshort8 vb = *(const vshort8*)(vtb + (long)(dt * 16 + lr) * SEQ + wid * 256 + j * 32 + lg * 8);
      o0[dt] = __builtin_amdgcn_mfma_f32_16x16x32_bf16(af0, vb, o0[dt], 0, 0, 0);
      o1[dt] = __builtin_amdgcn_mfma_f32_16x16x32_bf16(af1, vb, o1[dt], 0, 0, 0);
    }
  }

#pragma unroll
  for (int dt = 0; dt < 4; dt++)
#pragma unroll
    for (int r = 0; r < 4; r++) {
      *(float*)(Pw0 + ((lg * 4 + r) * 64 + dt * 16 + lr) * 4) = o0[dt][r];
      *(float*)(Pw1 + ((lg * 4 + r) * 64 + dt * 16 + lr) * 4) = o1[dt][r];
    }
  __syncthreads();

  const int q = tid >> 4, d0 = (tid & 15) * 4;
#pragma unroll
  for (int h = 0; h < 2; h++) {
    const int ro = h * 8192 + (q * 64 + d0) * 4;
    float4 a0 = *(const float4*)((const char*)P_lds + 0 * 16384 + ro);
    float4 a1 = *(const float4*)((const char*)P_lds + 1 * 16384 + ro);
    float4 a2 = *(const float4*)((const char*)P_lds + 2 * 16384 + ro);
    float4 a3 = *(const float4*)((const char*)P_lds + 3 * 16384 + ro);
    float ox = (a0.x + a1.x) + (a2.x + a3.x);
    float oy = (a0.y + a1.y) + (a2.y + a3.y);
    float oz = (a0.z + a1.z) + (a2.z + a3.z);
    float ow = (a0.w + a1.w) + (a2.w + a3.w);
    uint2 ob;
    ob.x = pk_bf16(ox, oy);
    ob.y = pk_bf16(oz, ow);
    *(uint2*)(o + (tokbase + qt * 32 + h * 16 + q) * CDIM + hh * HDIM + d0) = ob;
  }
}

extern "C" void kernel_launch(void* const* d_in, const int* in_sizes, int n_in,
                              void* d_out, int out_size, void* d_ws, size_t ws_size,
                              hipStream_t stream) {
  const float* x     = (const float*)d_in[0];
  const float* ln1_g = (const float*)d_in[1];
  const float* ln1_b = (const float*)d_in[2];
  const float* wqkv  = (const float*)d_in[3];
  const float* wproj = (const float*)d_in[4];
  const float* bproj = (const float*)d_in[5];
  const float* ln2_g = (const float*)d_in[6];
  const float* ln2_b = (const float*)d_in[7];
  const float* w1    = (const float*)d_in[8];
  const float* b1    = (const float*)d_in[9];
  const float* w2    = (const float*)d_in[10];
  const float* b2    = (const float*)d_in[11];
  float* h = (float*)d_out;

  char* ws = (char*)d_ws;
  short* wqkv_t  = (short*)ws; ws += (size_t)DEPTHL * QKVN * CDIM * 2;
  short* wproj_t = (short*)ws; ws += (size_t)DEPTHL * CDIM * CDIM * 2;
  short* w1_t    = (short*)ws; ws += (size_t)DEPTHL * MLPD * CDIM * 2;
  short* w2_t    = (short*)ws; ws += (size_t)DEPTHL * CDIM * MLPD * 2;
  short* ybf     = (short*)ws; ws += (size_t)TOK * CDIM * 2;
  short* qkvbf   = (short*)ws; ws += (size_t)TOK * QKVN * 2;
  short* obf     = (short*)ws; ws += (size_t)TOK * CDIM * 2;
  short* f1bf    = (short*)ws; ws += (size_t)TOK * MLPD * 2;
  short* vtb     = f1bf;   // overlay: vt lifetime disjoint from f1

  hipMemcpyAsync(h, x, (size_t)TOK * CDIM * sizeof(float), hipMemcpyDeviceToDevice, stream);

  wconv_t<<<dim3(QKVN / 32, CDIM / 32, DEPTHL), 256, 0, stream>>>(wqkv, wqkv_t, CDIM, QKVN);
  wconv_t<<<dim3(CDIM / 32, CDIM / 32, DEPTHL), 256, 0, stream>>>(wproj, wproj_t, CDIM, CDIM);
  wconv_t<<<dim3(MLPD / 32, CDIM / 32, DEPTHL), 256, 0, stream>>>(w1, w1_t, CDIM, MLPD);
  wconv_t<<<dim3(CDIM / 32, MLPD / 32, DEPTHL), 256, 0, stream>>>(w2, w2_t, MLPD, CDIM);

  for (int l = 0; l < DEPTHL; l++) {
    ln_fwd<<<TOK / 4, 256, 0, stream>>>(h, ln1_g + l * CDIM, ln1_b + l * CDIM, ybf);
    gemm_bt<3><<<dim3(QKVN / 128, TOK / 128), 256, 0, stream>>>(
        ybf, wqkv_t + (size_t)l * QKVN * CDIM, nullptr, qkvbf, vtb, TOK, QKVN, CDIM);
    attn_fused6<<<dim3(SEQ / 32, BZ * HEADS), 256, 0, stream>>>(qkvbf, vtb, obf);
    gemm_bt<2><<<dim3(CDIM / 128, TOK / 128), 256, 0, stream>>>(
        obf, wproj_t + (size_t)l * CDIM * CDIM, bproj + l * CDIM, h, nullptr, TOK, CDIM, CDIM);
    ln_fwd<<<TOK / 4, 256, 0, stream>>>(h, ln2_g + l * CDIM, ln2_b + l * CDIM, ybf);
    gemm_mk<1><<<dim3(MLPD / 128, TOK / 256), 512, 0, stream>>>(
        ybf, w1_t + (size_t)l * MLPD * CDIM, b1 + l * MLPD, f1bf, TOK, MLPD, CDIM);
    gemm_bt<2><<<dim3(CDIM / 128, TOK / 128), 256, 0, stream>>>(
        f1bf, w2_t + (size_t)l * CDIM * MLPD, b2 + l * CDIM, h, nullptr, TOK, CDIM, MLPD);
  }
}

// Round 15
// 3316.214 us; speedup vs baseline: 1.0770x; 1.0770x over previous
//
#include <hip/hip_runtime.h>
#include <hip/hip_bf16.h>

#define DEPTHL 8
#define BZ 8
#define SEQ 1024
#define CDIM 768
#define HEADS 12
#define HDIM 64
#define MLPD 3072
#define TOK (BZ*SEQ)      // 8192
#define QKVN (3*CDIM)     // 2304

typedef __attribute__((ext_vector_type(8))) short vshort8;
typedef __attribute__((ext_vector_type(4))) short vshort4;
typedef __attribute__((ext_vector_type(4))) float vfloat4;

__device__ __forceinline__ short bf16_bits(float f) {
  union { float f; unsigned u; } x; x.f = f;
  unsigned r = (x.u + 0x7FFFu + ((x.u >> 16) & 1u)) >> 16;
  return (short)r;
}

__device__ __forceinline__ unsigned pk_bf16(float a, float b) {
  unsigned r;
  asm("v_cvt_pk_bf16_f32 %0, %1, %2" : "=v"(r) : "v"(a), "v"(b));
  return r;   // low16 = bf16(a), high16 = bf16(b)
}

#define GL16(g, l) __builtin_amdgcn_global_load_lds( \
    (const __attribute__((address_space(1))) unsigned int*)(g), \
    (__attribute__((address_space(3))) unsigned int*)(l), 16, 0, 0)

// ---------------- weight convert + transpose: fp32 [D][K][N] -> bf16 [D][N][K]
__global__ __launch_bounds__(256) void wconv_t(const float* __restrict__ in,
                                               short* __restrict__ out,
                                               int K, int N) {
  __shared__ float tile[32][33];
  const long d = blockIdx.z;
  in  += d * (long)K * N;
  out += d * (long)N * K;
  const int n0 = blockIdx.x * 32, k0 = blockIdx.y * 32;
  const int tx = threadIdx.x & 31, ty = threadIdx.x >> 5;
#pragma unroll
  for (int i = 0; i < 4; i++)
    tile[ty + 8*i][tx] = in[(long)(k0 + ty + 8*i) * N + n0 + tx];
  __syncthreads();
#pragma unroll
  for (int i = 0; i < 4; i++)
    out[(long)(n0 + ty + 8*i) * K + k0 + tx] = bf16_bits(tile[tx][ty + 8*i]);
}

// ---------------- V transpose per head: qkv V-part [tok][d] -> vt [bh][d][tok]
__global__ __launch_bounds__(256) void vtrans(const short* __restrict__ qkv,
                                              short* __restrict__ vt) {
  __shared__ short tile[32][34];
  const int bh = blockIdx.z;
  const int b = bh / HEADS, hh = bh % HEADS;
  const int t0 = blockIdx.x * 32, d0 = blockIdx.y * 32;
  const int tx = threadIdx.x & 31, ty = threadIdx.x >> 5;
  const short* src = qkv + ((long)b * SEQ + t0) * QKVN + 2 * CDIM + hh * HDIM + d0;
#pragma unroll
  for (int i = 0; i < 4; i++)
    tile[ty + 8*i][tx] = src[(long)(ty + 8*i) * QKVN + tx];
  __syncthreads();
  short* dst = vt + (long)bh * HDIM * SEQ + (long)d0 * SEQ + t0;
#pragma unroll
  for (int i = 0; i < 4; i++)
    dst[(long)(ty + 8*i) * SEQ + tx] = tile[tx][ty + 8*i];
}

// ---------------- LayerNorm: 1 wave per row, 4 rows per block, shfl-only
__global__ __launch_bounds__(256) void ln_fwd(const float* __restrict__ h,
                                              const float* __restrict__ g,
                                              const float* __restrict__ be,
                                              short* __restrict__ y) {
  const int row = blockIdx.x * 4 + (threadIdx.x >> 6);
  const int lane = threadIdx.x & 63;
  const float4* hr = (const float4*)(h + (long)row * CDIM);
  const float4 v0 = hr[lane], v1 = hr[lane + 64], v2 = hr[lane + 128];
  float s = (v0.x + v0.y + v0.z + v0.w) + (v1.x + v1.y + v1.z + v1.w)
          + (v2.x + v2.y + v2.z + v2.w);
#pragma unroll
  for (int m = 32; m >= 1; m >>= 1) s += __shfl_xor(s, m);
  const float mu = s * (1.0f / CDIM);
  float d0x = v0.x - mu, d0y = v0.y - mu, d0z = v0.z - mu, d0w = v0.w - mu;
  float d1x = v1.x - mu, d1y = v1.y - mu, d1z = v1.z - mu, d1w = v1.w - mu;
  float d2x = v2.x - mu, d2y = v2.y - mu, d2z = v2.z - mu, d2w = v2.w - mu;
  float q = (d0x*d0x + d0y*d0y + d0z*d0z + d0w*d0w)
          + (d1x*d1x + d1y*d1y + d1z*d1z + d1w*d1w)
          + (d2x*d2x + d2y*d2y + d2z*d2z + d2w*d2w);
#pragma unroll
  for (int m = 32; m >= 1; m >>= 1) q += __shfl_xor(q, m);
  const float rstd = rsqrtf(q * (1.0f / CDIM) + 1e-5f);
  const float4* gp = (const float4*)g;
  const float4* bp = (const float4*)be;
  short* yr = y + (long)row * CDIM;
#pragma unroll
  for (int c = 0; c < 3; c++) {
    const float4 g4 = gp[lane + c * 64];
    const float4 b4 = bp[lane + c * 64];
    float dx = (c == 0 ? d0x : c == 1 ? d1x : d2x);
    float dy = (c == 0 ? d0y : c == 1 ? d1y : d2y);
    float dz = (c == 0 ? d0z : c == 1 ? d1z : d2z);
    float dw = (c == 0 ? d0w : c == 1 ? d1w : d2w);
    vshort4 o;
    o[0] = bf16_bits(dx * rstd * g4.x + b4.x);
    o[1] = bf16_bits(dy * rstd * g4.y + b4.y);
    o[2] = bf16_bits(dz * rstd * g4.z + b4.z);
    o[3] = bf16_bits(dw * rstd * g4.w + b4.w);
    *(vshort4*)(yr + c * 256 + lane * 4) = o;
  }
}

// ---------------- GEMM: 128x128 tile, BK=64 (best measured config, R9/R12)
template<int EPI>
__global__ __launch_bounds__(256) void gemm_bt(const short* __restrict__ A,
                                               const short* __restrict__ Bt,
                                               const float* __restrict__ bias,
                                               void* __restrict__ Cout,
                                               int M, int N, int K) {
  __shared__ short As[128 * 64];
  __shared__ short Bs[128 * 64];
  const int tid = threadIdx.x;
  const int wid = tid >> 6, lane = tid & 63;
  const int lg = lane >> 4, lr = lane & 15;
  const int wm = wid >> 1, wn = wid & 1;

  const int gx = gridDim.x;
  const int nwg = gx * gridDim.y;
  int flat = blockIdx.y * gx + blockIdx.x;
  flat = (flat & 7) * (nwg >> 3) + (flat >> 3);   // same-XCD blocks contiguous
  const long bx = flat % gx;
  const long by = flat / gx;

  vfloat4 acc[4][4];
#pragma unroll
  for (int i = 0; i < 4; i++)
#pragma unroll
    for (int j = 0; j < 4; j++) acc[i][j] = (vfloat4){0.f, 0.f, 0.f, 0.f};

  const short* Abase = A  + by * 128 * (long)K;
  const short* Bbase = Bt + bx * 128 * (long)K;

  for (int kk = 0; kk < K; kk += 64) {
    __syncthreads();
#pragma unroll
    for (int ch = 0; ch < 4; ch++) {
      const int dst = tid * 16 + ch * 4096;
      const int off = dst ^ (((dst >> 7) & 7) << 4);
      const long srow = off >> 7;
      const int scol = (off & 127) >> 1;
      GL16(Abase + srow * K + kk + scol, As + (dst >> 1));
      GL16(Bbase + srow * K + kk + scol, Bs + (dst >> 1));
    }
    __syncthreads();
#pragma unroll
    for (int kh = 0; kh < 2; kh++) {
      vshort8 a[4], b[4];
#pragma unroll
      for (int mt = 0; mt < 4; mt++) {
        const int row = wm * 64 + mt * 16 + lr;
        int byt = row * 128 + kh * 64 + lg * 16;
        byt ^= (row & 7) << 4;
        a[mt] = *(const vshort8*)((const char*)As + byt);
      }
#pragma unroll
      for (int nt = 0; nt < 4; nt++) {
        const int row = wn * 64 + nt * 16 + lr;
        int byt = row * 128 + kh * 64 + lg * 16;
        byt ^= (row & 7) << 4;
        b[nt] = *(const vshort8*)((const char*)Bs + byt);
      }
#pragma unroll
      for (int mt = 0; mt < 4; mt++)
#pragma unroll
        for (int nt = 0; nt < 4; nt++)
          acc[mt][nt] = __builtin_amdgcn_mfma_f32_16x16x32_bf16(a[mt], b[nt], acc[mt][nt], 0, 0, 0);
    }
  }

  const long row0 = by * 128 + wm * 64;
  const long col0 = bx * 128 + wn * 64;
#pragma unroll
  for (int mt = 0; mt < 4; mt++) {
#pragma unroll
    for (int nt = 0; nt < 4; nt++) {
      const long col = col0 + nt * 16 + lr;
      float bv = 0.f;
      if (EPI != 0) bv = bias[col];
#pragma unroll
      for (int r = 0; r < 4; r++) {
        const long row = row0 + mt * 16 + lg * 4 + r;
        float v = acc[mt][nt][r];
        if (EPI == 0) {
          ((short*)Cout)[row * N + col] = bf16_bits(v);
        } else if (EPI == 1) {
          v += bv; v = v > 0.f ? v : 0.f;
          ((short*)Cout)[row * N + col] = bf16_bits(v);
        } else {
          float* hp = (float*)Cout + row * N + col;
          *hp = *hp + v + bv;
        }
      }
    }
  }
}

// ---------------- fused attention v6 (best measured: 185us/dispatch)
__global__ __launch_bounds__(256) void attn_fused6(const short* __restrict__ qkv,
                                                   const short* __restrict__ vt,
                                                   short* __restrict__ o) {
  __shared__ __align__(16) short P_lds[4 * 2 * 4096];   // [wave][half][16q x 256kv]
  __shared__ float redm[4][16], redz[4][16], redt[4][16];
  int flat = blockIdx.y * 32 + blockIdx.x;          // nwg = 3072
  flat = (flat & 7) * (3072 >> 3) + (flat >> 3);    // 384/XCD = 12 heads
  const int qt = flat & 31;
  const int bh = flat >> 5;
  const int b = bh / HEADS, hh = bh % HEADS;
  const int tid = threadIdx.x, wid = tid >> 6, lane = tid & 63;
  const int lg = lane >> 4, lr = lane & 15;
  const long tokbase = (long)b * SEQ;
  const short* qbase = qkv + tokbase * QKVN + hh * HDIM;
  const short* kbase = qkv + tokbase * QKVN + CDIM + hh * HDIM;
  const short* vtb = vt + (long)bh * HDIM * SEQ;
  char* Pw0 = (char*)P_lds + wid * 16384;
  char* Pw1 = Pw0 + 8192;

  vshort8 qf0[2], qf1[2];
#pragma unroll
  for (int ks = 0; ks < 2; ks++) {
    qf0[ks] = *(const vshort8*)(qbase + (long)(qt * 32 + lr) * QKVN + ks * 32 + lg * 8);
    qf1[ks] = *(const vshort8*)(qbase + (long)(qt * 32 + 16 + lr) * QKVN + ks * 32 + lg * 8);
  }

  vfloat4 s0[16], s1[16];
#pragma unroll
  for (int bb = 0; bb < 4; bb++) {
    vshort8 kf[8];
#pragma unroll
    for (int u = 0; u < 4; u++) {
      const int n0 = wid * 256 + (bb * 4 + u) * 16;
#pragma unroll
      for (int ks = 0; ks < 2; ks++)
        kf[u * 2 + ks] = *(const vshort8*)(kbase + (long)(n0 + lr) * QKVN + ks * 32 + lg * 8);
    }
#pragma unroll
    for (int u = 0; u < 4; u++) {
      vfloat4 a0 = (vfloat4){0.f, 0.f, 0.f, 0.f};
      a0 = __builtin_amdgcn_mfma_f32_16x16x32_bf16(kf[u * 2 + 0], qf0[0], a0, 0, 0, 0);
      a0 = __builtin_amdgcn_mfma_f32_16x16x32_bf16(kf[u * 2 + 1], qf0[1], a0, 0, 0, 0);
      s0[bb * 4 + u] = a0;
      vfloat4 a1 = (vfloat4){0.f, 0.f, 0.f, 0.f};
      a1 = __builtin_amdgcn_mfma_f32_16x16x32_bf16(kf[u * 2 + 0], qf1[0], a1, 0, 0, 0);
      a1 = __builtin_amdgcn_mfma_f32_16x16x32_bf16(kf[u * 2 + 1], qf1[1], a1, 0, 0, 0);
      s1[bb * 4 + u] = a1;
    }
  }

  float rt0, rt1;
#define SOFTMAX_HALF(S, RT)                                                   \
  {                                                                           \
    float mt16[16];                                                           \
    _Pragma("unroll")                                                         \
    for (int i = 0; i < 16; i++)                                              \
      mt16[i] = fmaxf(fmaxf(S[i][0], S[i][1]), fmaxf(S[i][2], S[i][3]));      \
    _Pragma("unroll")                                                         \
    for (int st = 8; st >= 1; st >>= 1)                                       \
      _Pragma("unroll")                                                       \
      for (int i = 0; i < 8; i++) if (i < st) mt16[i] = fmaxf(mt16[i], mt16[i + st]); \
    float m = mt16[0];                                                        \
    m = fmaxf(m, __shfl_xor(m, 16));                                          \
    m = fmaxf(m, __shfl_xor(m, 32));                                          \
    if (lane < 16) redm[wid][lr] = m;                                         \
    __syncthreads();                                                          \
    m = fmaxf(fmaxf(redm[0][lr], redm[1][lr]), fmaxf(redm[2][lr], redm[3][lr])); \
    const float msc = m * 0.125f;                                             \
    float zt[16];                                                             \
    _Pragma("unroll")                                                         \
    for (int i = 0; i < 16; i++) {                                            \
      float e0 = __expf(fmaf(S[i][0], 0.125f, -msc));                         \
      float e1 = __expf(fmaf(S[i][1], 0.125f, -msc));                         \
      float e2 = __expf(fmaf(S[i][2], 0.125f, -msc));                         \
      float e3 = __expf(fmaf(S[i][3], 0.125f, -msc));                         \
      S[i][0] = e0; S[i][1] = e1; S[i][2] = e2; S[i][3] = e3;                 \
      zt[i] = (e0 + e1) + (e2 + e3);                                          \
    }                                                                         \
    _Pragma("unroll")                                                         \
    for (int st = 8; st >= 1; st >>= 1)                                       \
      _Pragma("unroll")                                                       \
      for (int i = 0; i < 8; i++) if (i < st) zt[i] += zt[i + st];            \
    float z = zt[0];                                                          \
    z += __shfl_xor(z, 16);                                                   \
    z += __shfl_xor(z, 32);                                                   \
    if (lane < 16) redz[wid][lr] = z;                                         \
    __syncthreads();                                                          \
    z = (redz[0][lr] + redz[1][lr]) + (redz[2][lr] + redz[3][lr]);            \
    const float rz = 1.0f / z;                                                \
    float tt[16];                                                             \
    _Pragma("unroll")                                                         \
    for (int i = 0; i < 16; i++) {                                            \
      float p0 = __expf(S[i][0] * rz);                                        \
      float p1 = __expf(S[i][1] * rz);                                        \
      float p2 = __expf(S[i][2] * rz);                                        \
      float p3 = __expf(S[i][3] * rz);                                        \
      S[i][0] = p0; S[i][1] = p1; S[i][2] = p2; S[i][3] = p3;                 \
      tt[i] = (p0 + p1) + (p2 + p3);                                          \
    }                                                                         \
    _Pragma("unroll")                                                         \
    for (int st = 8; st >= 1; st >>= 1)                                       \
      _Pragma("unroll")                                                       \
      for (int i = 0; i < 8; i++) if (i < st) tt[i] += tt[i + st];            \
    float t2 = tt[0];                                                         \
    t2 += __shfl_xor(t2, 16);                                                 \
    t2 += __shfl_xor(t2, 32);                                                 \
    if (lane < 16) redt[wid][lr] = t2;                                        \
    __syncthreads();                                                          \
    t2 = (redt[0][lr] + redt[1][lr]) + (redt[2][lr] + redt[3][lr]);           \
    RT = 1.0f / t2;                                                           \
  }

  SOFTMAX_HALF(s0, rt0)
  SOFTMAX_HALF(s1, rt1)
#undef SOFTMAX_HALF

#pragma unroll
  for (int i = 0; i < 16; i++) {
    const int byt = (lr * 512 + i * 32 + lg * 8) ^ ((lr & 7) << 4);
    uint2 pk0, pk1;
    pk0.x = pk_bf16(s0[i][0] * rt0, s0[i][1] * rt0);
    pk0.y = pk_bf16(s0[i][2] * rt0, s0[i][3] * rt0);
    pk1.x = pk_bf16(s1[i][0] * rt1, s1[i][1] * rt1);
    pk1.y = pk_bf16(s1[i][2] * rt1, s1[i][3] * rt1);
    *(uint2*)(Pw0 + byt) = pk0;
    *(uint2*)(Pw1 + byt) = pk1;
  }

  vfloat4 o0[4], o1[4];
#pragma unroll
  for (int dt = 0; dt < 4; dt++) {
    o0[dt] = (vfloat4){0.f, 0.f, 0.f, 0.f};
    o1[dt] = (vfloat4){0.f, 0.f, 0.f, 0.f};
  }
#pragma unroll
  for (int j = 0; j < 8; j++) {
    const int abyt = (lr * 512 + j * 64 + lg * 16) ^ ((lr & 7) << 4);
    vshort8 af0 = *(const vshort8*)(Pw0 + abyt);
    vshort8 af1 = *(const vshort8*)(Pw1 + abyt);
#pragma unroll
    for (int dt = 0; dt < 4; dt++) {
      vshort8 vb = *(const vshort8*)(vtb + (long)(dt * 16 + lr) * SEQ + wid * 256 + j * 32 + lg * 8);
      o0[dt] = __builtin_amdgcn_mfma_f32_16x16x32_bf16(af0, vb, o0[dt], 0, 0, 0);
      o1[dt] = __builtin_amdgcn_mfma_f32_16x16x32_bf16(af1, vb, o1[dt], 0, 0, 0);
    }
  }

#pragma unroll
  for (int dt = 0; dt < 4; dt++)
#pragma unroll
    for (int r = 0; r < 4; r++) {
      *(float*)(Pw0 + ((lg * 4 + r) * 64 + dt * 16 + lr) * 4) = o0[dt][r];
      *(float*)(Pw1 + ((lg * 4 + r) * 64 + dt * 16 + lr) * 4) = o1[dt][r];
    }
  __syncthreads();

  const int q = tid >> 4, d0 = (tid & 15) * 4;
#pragma unroll
  for (int h = 0; h < 2; h++) {
    const int ro = h * 8192 + (q * 64 + d0) * 4;
    float4 a0 = *(const float4*)((const char*)P_lds + 0 * 16384 + ro);
    float4 a1 = *(const float4*)((const char*)P_lds + 1 * 16384 + ro);
    float4 a2 = *(const float4*)((const char*)P_lds + 2 * 16384 + ro);
    float4 a3 = *(const float4*)((const char*)P_lds + 3 * 16384 + ro);
    float ox = (a0.x + a1.x) + (a2.x + a3.x);
    float oy = (a0.y + a1.y) + (a2.y + a3.y);
    float oz = (a0.z + a1.z) + (a2.z + a3.z);
    float ow = (a0.w + a1.w) + (a2.w + a3.w);
    uint2 ob;
    ob.x = pk_bf16(ox, oy);
    ob.y = pk_bf16(oz, ow);
    *(uint2*)(o + (tokbase + qt * 32 + h * 16 + q) * CDIM + hh * HDIM + d0) = ob;
  }
}

extern "C" void kernel_launch(void* const* d_in, const int* in_sizes, int n_in,
                              void* d_out, int out_size, void* d_ws, size_t ws_size,
                              hipStream_t stream) {
  const float* x     = (const float*)d_in[0];
  const float* ln1_g = (const float*)d_in[1];
  const float* ln1_b = (const float*)d_in[2];
  const float* wqkv  = (const float*)d_in[3];
  const float* wproj = (const float*)d_in[4];
  const float* bproj = (const float*)d_in[5];
  const float* ln2_g = (const float*)d_in[6];
  const float* ln2_b = (const float*)d_in[7];
  const float* w1    = (const float*)d_in[8];
  const float* b1    = (const float*)d_in[9];
  const float* w2    = (const float*)d_in[10];
  const float* b2    = (const float*)d_in[11];
  float* h = (float*)d_out;

  char* ws = (char*)d_ws;
  short* wqkv_t  = (short*)ws; ws += (size_t)DEPTHL * QKVN * CDIM * 2;
  short* wproj_t = (short*)ws; ws += (size_t)DEPTHL * CDIM * CDIM * 2;
  short* w1_t    = (short*)ws; ws += (size_t)DEPTHL * MLPD * CDIM * 2;
  short* w2_t    = (short*)ws; ws += (size_t)DEPTHL * CDIM * MLPD * 2;
  short* ybf     = (short*)ws; ws += (size_t)TOK * CDIM * 2;
  short* qkvbf   = (short*)ws; ws += (size_t)TOK * QKVN * 2;
  short* obf     = (short*)ws; ws += (size_t)TOK * CDIM * 2;
  short* f1bf    = (short*)ws; ws += (size_t)TOK * MLPD * 2;
  short* vtb     = f1bf;   // overlay: vt lifetime disjoint from f1

  hipMemcpyAsync(h, x, (size_t)TOK * CDIM * sizeof(float), hipMemcpyDeviceToDevice, stream);

  wconv_t<<<dim3(QKVN / 32, CDIM / 32, DEPTHL), 256, 0, stream>>>(wqkv, wqkv_t, CDIM, QKVN);
  wconv_t<<<dim3(CDIM / 32, CDIM / 32, DEPTHL), 256, 0, stream>>>(wproj, wproj_t, CDIM, CDIM);
  wconv_t<<<dim3(MLPD / 32, CDIM / 32, DEPTHL), 256, 0, stream>>>(w1, w1_t, CDIM, MLPD);
  wconv_t<<<dim3(CDIM / 32, MLPD / 32, DEPTHL), 256, 0, stream>>>(w2, w2_t, MLPD, CDIM);

  for (int l = 0; l < DEPTHL; l++) {
    ln_fwd<<<TOK / 4, 256, 0, stream>>>(h, ln1_g + l * CDIM, ln1_b + l * CDIM, ybf);
    gemm_bt<0><<<dim3(QKVN / 128, TOK / 128), 256, 0, stream>>>(
        ybf, wqkv_t + (size_t)l * QKVN * CDIM, nullptr, qkvbf, TOK, QKVN, CDIM);
    vtrans<<<dim3(SEQ / 32, HDIM / 32, BZ * HEADS), 256, 0, stream>>>(qkvbf, vtb);
    attn_fused6<<<dim3(SEQ / 32, BZ * HEADS), 256, 0, stream>>>(qkvbf, vtb, obf);
    gemm_bt<2><<<dim3(CDIM / 128, TOK / 128), 256, 0, stream>>>(
        obf, wproj_t + (size_t)l * CDIM * CDIM, bproj + l * CDIM, h, TOK, CDIM, CDIM);
    ln_fwd<<<TOK / 4, 256, 0, stream>>>(h, ln2_g + l * CDIM, ln2_b + l * CDIM, ybf);
    gemm_bt<1><<<dim3(MLPD / 128, TOK / 128), 256, 0, stream>>>(
        ybf, w1_t + (size_t)l * MLPD * CDIM, b1 + l * MLPD, f1bf, TOK, MLPD, CDIM);
    gemm_bt<2><<<dim3(CDIM / 128, TOK / 128), 256, 0, stream>>>(
        f1bf, w2_t + (size_t)l * CDIM * MLPD, b2 + l * CDIM, h, TOK, CDIM, MLPD);
  }
}

// Round 16
// 3248.393 us; speedup vs baseline: 1.0995x; 1.0209x over previous
//
#include <hip/hip_runtime.h>
#include <hip/hip_bf16.h>

#define DEPTHL 8
#define BZ 8
#define SEQ 1024
#define CDIM 768
#define HEADS 12
#define HDIM 64
#define MLPD 3072
#define TOK (BZ*SEQ)      // 8192
#define QKVN (3*CDIM)     // 2304

typedef __attribute__((ext_vector_type(8))) short vshort8;
typedef __attribute__((ext_vector_type(4))) short vshort4;
typedef __attribute__((ext_vector_type(4))) float vfloat4;

__device__ __forceinline__ short bf16_bits(float f) {
  union { float f; unsigned u; } x; x.f = f;
  unsigned r = (x.u + 0x7FFFu + ((x.u >> 16) & 1u)) >> 16;
  return (short)r;
}

__device__ __forceinline__ unsigned pk_bf16(float a, float b) {
  unsigned r;
  asm("v_cvt_pk_bf16_f32 %0, %1, %2" : "=v"(r) : "v"(a), "v"(b));
  return r;   // low16 = bf16(a), high16 = bf16(b)
}

#define GL16(g, l) __builtin_amdgcn_global_load_lds( \
    (const __attribute__((address_space(1))) unsigned int*)(g), \
    (__attribute__((address_space(3))) unsigned int*)(l), 16, 0, 0)

// ---------------- weight convert + transpose: fp32 [D][K][N] -> bf16 [D][N][K]
__global__ __launch_bounds__(256) void wconv_t(const float* __restrict__ in,
                                               short* __restrict__ out,
                                               int K, int N) {
  __shared__ float tile[32][33];
  const long d = blockIdx.z;
  in  += d * (long)K * N;
  out += d * (long)N * K;
  const int n0 = blockIdx.x * 32, k0 = blockIdx.y * 32;
  const int tx = threadIdx.x & 31, ty = threadIdx.x >> 5;
#pragma unroll
  for (int i = 0; i < 4; i++)
    tile[ty + 8*i][tx] = in[(long)(k0 + ty + 8*i) * N + n0 + tx];
  __syncthreads();
#pragma unroll
  for (int i = 0; i < 4; i++)
    out[(long)(n0 + ty + 8*i) * K + k0 + tx] = bf16_bits(tile[tx][ty + 8*i]);
}

// ---------------- V transpose per head: qkv V-part [tok][d] -> vt [bh][d][tok]
__global__ __launch_bounds__(256) void vtrans(const short* __restrict__ qkv,
                                              short* __restrict__ vt) {
  __shared__ short tile[32][34];
  const int bh = blockIdx.z;
  const int b = bh / HEADS, hh = bh % HEADS;
  const int t0 = blockIdx.x * 32, d0 = blockIdx.y * 32;
  const int tx = threadIdx.x & 31, ty = threadIdx.x >> 5;
  const short* src = qkv + ((long)b * SEQ + t0) * QKVN + 2 * CDIM + hh * HDIM + d0;
#pragma unroll
  for (int i = 0; i < 4; i++)
    tile[ty + 8*i][tx] = src[(long)(ty + 8*i) * QKVN + tx];
  __syncthreads();
  short* dst = vt + (long)bh * HDIM * SEQ + (long)d0 * SEQ + t0;
#pragma unroll
  for (int i = 0; i < 4; i++)
    dst[(long)(ty + 8*i) * SEQ + tx] = tile[tx][ty + 8*i];
}

// ---------------- LayerNorm: 1 wave per row, 4 rows per block, shfl-only
__global__ __launch_bounds__(256) void ln_fwd(const float* __restrict__ h,
                                              const float* __restrict__ g,
                                              const float* __restrict__ be,
                                              short* __restrict__ y) {
  const int row = blockIdx.x * 4 + (threadIdx.x >> 6);
  const int lane = threadIdx.x & 63;
  const float4* hr = (const float4*)(h + (long)row * CDIM);
  const float4 v0 = hr[lane], v1 = hr[lane + 64], v2 = hr[lane + 128];
  float s = (v0.x + v0.y + v0.z + v0.w) + (v1.x + v1.y + v1.z + v1.w)
          + (v2.x + v2.y + v2.z + v2.w);
#pragma unroll
  for (int m = 32; m >= 1; m >>= 1) s += __shfl_xor(s, m);
  const float mu = s * (1.0f / CDIM);
  float d0x = v0.x - mu, d0y = v0.y - mu, d0z = v0.z - mu, d0w = v0.w - mu;
  float d1x = v1.x - mu, d1y = v1.y - mu, d1z = v1.z - mu, d1w = v1.w - mu;
  float d2x = v2.x - mu, d2y = v2.y - mu, d2z = v2.z - mu, d2w = v2.w - mu;
  float q = (d0x*d0x + d0y*d0y + d0z*d0z + d0w*d0w)
          + (d1x*d1x + d1y*d1y + d1z*d1z + d1w*d1w)
          + (d2x*d2x + d2y*d2y + d2z*d2z + d2w*d2w);
#pragma unroll
  for (int m = 32; m >= 1; m >>= 1) q += __shfl_xor(q, m);
  const float rstd = rsqrtf(q * (1.0f / CDIM) + 1e-5f);
  const float4* gp = (const float4*)g;
  const float4* bp = (const float4*)be;
  short* yr = y + (long)row * CDIM;
#pragma unroll
  for (int c = 0; c < 3; c++) {
    const float4 g4 = gp[lane + c * 64];
    const float4 b4 = bp[lane + c * 64];
    float dx = (c == 0 ? d0x : c == 1 ? d1x : d2x);
    float dy = (c == 0 ? d0y : c == 1 ? d1y : d2y);
    float dz = (c == 0 ? d0z : c == 1 ? d1z : d2z);
    float dw = (c == 0 ? d0w : c == 1 ? d1w : d2w);
    vshort4 o;
    o[0] = bf16_bits(dx * rstd * g4.x + b4.x);
    o[1] = bf16_bits(dy * rstd * g4.y + b4.y);
    o[2] = bf16_bits(dz * rstd * g4.z + b4.z);
    o[3] = bf16_bits(dw * rstd * g4.w + b4.w);
    *(vshort4*)(yr + c * 256 + lane * 4) = o;
  }
}

// ---------------- GEMM: 128x128 tile, BK=64 (best measured config, R9/R12)
template<int EPI>
__global__ __launch_bounds__(256) void gemm_bt(const short* __restrict__ A,
                                               const short* __restrict__ Bt,
                                               const float* __restrict__ bias,
                                               void* __restrict__ Cout,
                                               int M, int N, int K) {
  __shared__ short As[128 * 64];
  __shared__ short Bs[128 * 64];
  const int tid = threadIdx.x;
  const int wid = tid >> 6, lane = tid & 63;
  const int lg = lane >> 4, lr = lane & 15;
  const int wm = wid >> 1, wn = wid & 1;

  const int gx = gridDim.x;
  const int nwg = gx * gridDim.y;
  int flat = blockIdx.y * gx + blockIdx.x;
  flat = (flat & 7) * (nwg >> 3) + (flat >> 3);   // same-XCD blocks contiguous
  const long bx = flat % gx;
  const long by = flat / gx;

  vfloat4 acc[4][4];
#pragma unroll
  for (int i = 0; i < 4; i++)
#pragma unroll
    for (int j = 0; j < 4; j++) acc[i][j] = (vfloat4){0.f, 0.f, 0.f, 0.f};

  const short* Abase = A  + by * 128 * (long)K;
  const short* Bbase = Bt + bx * 128 * (long)K;

  for (int kk = 0; kk < K; kk += 64) {
    __syncthreads();
#pragma unroll
    for (int ch = 0; ch < 4; ch++) {
      const int dst = tid * 16 + ch * 4096;
      const int off = dst ^ (((dst >> 7) & 7) << 4);
      const long srow = off >> 7;
      const int scol = (off & 127) >> 1;
      GL16(Abase + srow * K + kk + scol, As + (dst >> 1));
      GL16(Bbase + srow * K + kk + scol, Bs + (dst >> 1));
    }
    __syncthreads();
#pragma unroll
    for (int kh = 0; kh < 2; kh++) {
      vshort8 a[4], b[4];
#pragma unroll
      for (int mt = 0; mt < 4; mt++) {
        const int row = wm * 64 + mt * 16 + lr;
        int byt = row * 128 + kh * 64 + lg * 16;
        byt ^= (row & 7) << 4;
        a[mt] = *(const vshort8*)((const char*)As + byt);
      }
#pragma unroll
      for (int nt = 0; nt < 4; nt++) {
        const int row = wn * 64 + nt * 16 + lr;
        int byt = row * 128 + kh * 64 + lg * 16;
        byt ^= (row & 7) << 4;
        b[nt] = *(const vshort8*)((const char*)Bs + byt);
      }
#pragma unroll
      for (int mt = 0; mt < 4; mt++)
#pragma unroll
        for (int nt = 0; nt < 4; nt++)
          acc[mt][nt] = __builtin_amdgcn_mfma_f32_16x16x32_bf16(a[mt], b[nt], acc[mt][nt], 0, 0, 0);
    }
  }

  const long row0 = by * 128 + wm * 64;
  const long col0 = bx * 128 + wn * 64;
#pragma unroll
  for (int mt = 0; mt < 4; mt++) {
#pragma unroll
    for (int nt = 0; nt < 4; nt++) {
      const long col = col0 + nt * 16 + lr;
      float bv = 0.f;
      if (EPI != 0) bv = bias[col];
#pragma unroll
      for (int r = 0; r < 4; r++) {
        const long row = row0 + mt * 16 + lg * 4 + r;
        float v = acc[mt][nt][r];
        if (EPI == 0) {
          ((short*)Cout)[row * N + col] = bf16_bits(v);
        } else if (EPI == 1) {
          v += bv; v = v > 0.f ? v : 0.f;
          ((short*)Cout)[row * N + col] = bf16_bits(v);
        } else {
          float* hp = (float*)Cout + row * N + col;
          *hp = *hp + v + bv;
        }
      }
    }
  }
}

// ---------------- fused attention v7: v6 + interleaved dual-softmax
// (both q-halves' reduction chains run interleaved; barriers 7 -> 4; every
// latency element has an independent sibling for dual-issue)
__global__ __launch_bounds__(256) void attn_fused7(const short* __restrict__ qkv,
                                                   const short* __restrict__ vt,
                                                   short* __restrict__ o) {
  __shared__ __align__(16) short P_lds[4 * 2 * 4096];   // [wave][half][16q x 256kv]
  __shared__ float redm[2][4][16], redz[2][4][16], redt[2][4][16];
  int flat = blockIdx.y * 32 + blockIdx.x;          // nwg = 3072
  flat = (flat & 7) * (3072 >> 3) + (flat >> 3);    // 384/XCD = 12 heads
  const int qt = flat & 31;
  const int bh = flat >> 5;
  const int b = bh / HEADS, hh = bh % HEADS;
  const int tid = threadIdx.x, wid = tid >> 6, lane = tid & 63;
  const int lg = lane >> 4, lr = lane & 15;
  const long tokbase = (long)b * SEQ;
  const short* qbase = qkv + tokbase * QKVN + hh * HDIM;
  const short* kbase = qkv + tokbase * QKVN + CDIM + hh * HDIM;
  const short* vtb = vt + (long)bh * HDIM * SEQ;
  char* Pw0 = (char*)P_lds + wid * 16384;
  char* Pw1 = Pw0 + 8192;

  vshort8 qf0[2], qf1[2];
#pragma unroll
  for (int ks = 0; ks < 2; ks++) {
    qf0[ks] = *(const vshort8*)(qbase + (long)(qt * 32 + lr) * QKVN + ks * 32 + lg * 8);
    qf1[ks] = *(const vshort8*)(qbase + (long)(qt * 32 + 16 + lr) * QKVN + ks * 32 + lg * 8);
  }

  // ---- Phase 1: S^T = K @ Q^T for both halves; each kf batch used twice
  vfloat4 s0[16], s1[16];
#pragma unroll
  for (int bb = 0; bb < 4; bb++) {
    vshort8 kf[8];
#pragma unroll
    for (int u = 0; u < 4; u++) {
      const int n0 = wid * 256 + (bb * 4 + u) * 16;
#pragma unroll
      for (int ks = 0; ks < 2; ks++)
        kf[u * 2 + ks] = *(const vshort8*)(kbase + (long)(n0 + lr) * QKVN + ks * 32 + lg * 8);
    }
#pragma unroll
    for (int u = 0; u < 4; u++) {
      vfloat4 a0 = (vfloat4){0.f, 0.f, 0.f, 0.f};
      a0 = __builtin_amdgcn_mfma_f32_16x16x32_bf16(kf[u * 2 + 0], qf0[0], a0, 0, 0, 0);
      a0 = __builtin_amdgcn_mfma_f32_16x16x32_bf16(kf[u * 2 + 1], qf0[1], a0, 0, 0, 0);
      s0[bb * 4 + u] = a0;
      vfloat4 a1 = (vfloat4){0.f, 0.f, 0.f, 0.f};
      a1 = __builtin_amdgcn_mfma_f32_16x16x32_bf16(kf[u * 2 + 0], qf1[0], a1, 0, 0, 0);
      a1 = __builtin_amdgcn_mfma_f32_16x16x32_bf16(kf[u * 2 + 1], qf1[1], a1, 0, 0, 0);
      s1[bb * 4 + u] = a1;
    }
  }

  // ---- Phase 2: interleaved dual double-softmax (3 barriers total)
  float mtA[16], mtB[16];
#pragma unroll
  for (int i = 0; i < 16; i++) {
    mtA[i] = fmaxf(fmaxf(s0[i][0], s0[i][1]), fmaxf(s0[i][2], s0[i][3]));
    mtB[i] = fmaxf(fmaxf(s1[i][0], s1[i][1]), fmaxf(s1[i][2], s1[i][3]));
  }
#pragma unroll
  for (int st = 8; st >= 1; st >>= 1)
#pragma unroll
    for (int i = 0; i < 8; i++)
      if (i < st) { mtA[i] = fmaxf(mtA[i], mtA[i + st]); mtB[i] = fmaxf(mtB[i], mtB[i + st]); }
  float mA = mtA[0], mB = mtB[0];
  mA = fmaxf(mA, __shfl_xor(mA, 16));  mB = fmaxf(mB, __shfl_xor(mB, 16));
  mA = fmaxf(mA, __shfl_xor(mA, 32));  mB = fmaxf(mB, __shfl_xor(mB, 32));
  if (lane < 16) { redm[0][wid][lr] = mA; redm[1][wid][lr] = mB; }
  __syncthreads();
  mA = fmaxf(fmaxf(redm[0][0][lr], redm[0][1][lr]), fmaxf(redm[0][2][lr], redm[0][3][lr]));
  mB = fmaxf(fmaxf(redm[1][0][lr], redm[1][1][lr]), fmaxf(redm[1][2][lr], redm[1][3][lr]));
  const float mscA = mA * 0.125f, mscB = mB * 0.125f;

  float ztA[16], ztB[16];
#pragma unroll
  for (int i = 0; i < 16; i++) {
    float a0 = __expf(fmaf(s0[i][0], 0.125f, -mscA));
    float b0 = __expf(fmaf(s1[i][0], 0.125f, -mscB));
    float a1 = __expf(fmaf(s0[i][1], 0.125f, -mscA));
    float b1 = __expf(fmaf(s1[i][1], 0.125f, -mscB));
    float a2 = __expf(fmaf(s0[i][2], 0.125f, -mscA));
    float b2 = __expf(fmaf(s1[i][2], 0.125f, -mscB));
    float a3 = __expf(fmaf(s0[i][3], 0.125f, -mscA));
    float b3 = __expf(fmaf(s1[i][3], 0.125f, -mscB));
    s0[i][0] = a0; s0[i][1] = a1; s0[i][2] = a2; s0[i][3] = a3;
    s1[i][0] = b0; s1[i][1] = b1; s1[i][2] = b2; s1[i][3] = b3;
    ztA[i] = (a0 + a1) + (a2 + a3);
    ztB[i] = (b0 + b1) + (b2 + b3);
  }
#pragma unroll
  for (int st = 8; st >= 1; st >>= 1)
#pragma unroll
    for (int i = 0; i < 8; i++)
      if (i < st) { ztA[i] += ztA[i + st]; ztB[i] += ztB[i + st]; }
  float zA = ztA[0], zB = ztB[0];
  zA += __shfl_xor(zA, 16);  zB += __shfl_xor(zB, 16);
  zA += __shfl_xor(zA, 32);  zB += __shfl_xor(zB, 32);
  if (lane < 16) { redz[0][wid][lr] = zA; redz[1][wid][lr] = zB; }
  __syncthreads();
  zA = (redz[0][0][lr] + redz[0][1][lr]) + (redz[0][2][lr] + redz[0][3][lr]);
  zB = (redz[1][0][lr] + redz[1][1][lr]) + (redz[1][2][lr] + redz[1][3][lr]);
  const float rzA = 1.0f / zA, rzB = 1.0f / zB;

  float ttA[16], ttB[16];
#pragma unroll
  for (int i = 0; i < 16; i++) {
    float a0 = __expf(s0[i][0] * rzA);
    float b0 = __expf(s1[i][0] * rzB);
    float a1 = __expf(s0[i][1] * rzA);
    float b1 = __expf(s1[i][1] * rzB);
    float a2 = __expf(s0[i][2] * rzA);
    float b2 = __expf(s1[i][2] * rzB);
    float a3 = __expf(s0[i][3] * rzA);
    float b3 = __expf(s1[i][3] * rzB);
    s0[i][0] = a0; s0[i][1] = a1; s0[i][2] = a2; s0[i][3] = a3;
    s1[i][0] = b0; s1[i][1] = b1; s1[i][2] = b2; s1[i][3] = b3;
    ttA[i] = (a0 + a1) + (a2 + a3);
    ttB[i] = (b0 + b1) + (b2 + b3);
  }
#pragma unroll
  for (int st = 8; st >= 1; st >>= 1)
#pragma unroll
    for (int i = 0; i < 8; i++)
      if (i < st) { ttA[i] += ttA[i + st]; ttB[i] += ttB[i + st]; }
  float tA = ttA[0], tB = ttB[0];
  tA += __shfl_xor(tA, 16);  tB += __shfl_xor(tB, 16);
  tA += __shfl_xor(tA, 32);  tB += __shfl_xor(tB, 32);
  if (lane < 16) { redt[0][wid][lr] = tA; redt[1][wid][lr] = tB; }
  __syncthreads();
  tA = (redt[0][0][lr] + redt[0][1][lr]) + (redt[0][2][lr] + redt[0][3][lr]);
  tB = (redt[1][0][lr] + redt[1][1][lr]) + (redt[1][2][lr] + redt[1][3][lr]);
  const float rt0 = 1.0f / tA, rt1 = 1.0f / tB;

  // ---- pack both halves' P into per-wave LDS regions (wave-private)
#pragma unroll
  for (int i = 0; i < 16; i++) {
    const int byt = (lr * 512 + i * 32 + lg * 8) ^ ((lr & 7) << 4);
    uint2 pk0, pk1;
    pk0.x = pk_bf16(s0[i][0] * rt0, s0[i][1] * rt0);
    pk0.y = pk_bf16(s0[i][2] * rt0, s0[i][3] * rt0);
    pk1.x = pk_bf16(s1[i][0] * rt1, s1[i][1] * rt1);
    pk1.y = pk_bf16(s1[i][2] * rt1, s1[i][3] * rt1);
    *(uint2*)(Pw0 + byt) = pk0;
    *(uint2*)(Pw1 + byt) = pk1;
  }

  // ---- Phase 3: one V pass serves both halves
  vfloat4 o0[4], o1[4];
#pragma unroll
  for (int dt = 0; dt < 4; dt++) {
    o0[dt] = (vfloat4){0.f, 0.f, 0.f, 0.f};
    o1[dt] = (vfloat4){0.f, 0.f, 0.f, 0.f};
  }
#pragma unroll
  for (int j = 0; j < 8; j++) {
    const int abyt = (lr * 512 + j * 64 + lg * 16) ^ ((lr & 7) << 4);
    vshort8 af0 = *(const vshort8*)(Pw0 + abyt);
    vshort8 af1 = *(const vshort8*)(Pw1 + abyt);
#pragma unroll
    for (int dt = 0; dt < 4; dt++) {
      vshort8 vb = *(const vshort8*)(vtb + (long)(dt * 16 + lr) * SEQ + wid * 256 + j * 32 + lg * 8);
      o0[dt] = __builtin_amdgcn_mfma_f32_16x16x32_bf16(af0, vb, o0[dt], 0, 0, 0);
      o1[dt] = __builtin_amdgcn_mfma_f32_16x16x32_bf16(af1, vb, o1[dt], 0, 0, 0);
    }
  }

  // ---- O block-reduce
#pragma unroll
  for (int dt = 0; dt < 4; dt++)
#pragma unroll
    for (int r = 0; r < 4; r++) {
      *(float*)(Pw0 + ((lg * 4 + r) * 64 + dt * 16 + lr) * 4) = o0[dt][r];
      *(float*)(Pw1 + ((lg * 4 + r) * 64 + dt * 16 + lr) * 4) = o1[dt][r];
    }
  __syncthreads();

  const int q = tid >> 4, d0 = (tid & 15) * 4;
#pragma unroll
  for (int h = 0; h < 2; h++) {
    const int ro = h * 8192 + (q * 64 + d0) * 4;
    float4 a0 = *(const float4*)((const char*)P_lds + 0 * 16384 + ro);
    float4 a1 = *(const float4*)((const char*)P_lds + 1 * 16384 + ro);
    float4 a2 = *(const float4*)((const char*)P_lds + 2 * 16384 + ro);
    float4 a3 = *(const float4*)((const char*)P_lds + 3 * 16384 + ro);
    float ox = (a0.x + a1.x) + (a2.x + a3.x);
    float oy = (a0.y + a1.y) + (a2.y + a3.y);
    float oz = (a0.z + a1.z) + (a2.z + a3.z);
    float ow = (a0.w + a1.w) + (a2.w + a3.w);
    uint2 ob;
    ob.x = pk_bf16(ox, oy);
    ob.y = pk_bf16(oz, ow);
    *(uint2*)(o + (tokbase + qt * 32 + h * 16 + q) * CDIM + hh * HDIM + d0) = ob;
  }
}

extern "C" void kernel_launch(void* const* d_in, const int* in_sizes, int n_in,
                              void* d_out, int out_size, void* d_ws, size_t ws_size,
                              hipStream_t stream) {
  const float* x     = (const float*)d_in[0];
  const float* ln1_g = (const float*)d_in[1];
  const float* ln1_b = (const float*)d_in[2];
  const float* wqkv  = (const float*)d_in[3];
  const float* wproj = (const float*)d_in[4];
  const float* bproj = (const float*)d_in[5];
  const float* ln2_g = (const float*)d_in[6];
  const float* ln2_b = (const float*)d_in[7];
  const float* w1    = (const float*)d_in[8];
  const float* b1    = (const float*)d_in[9];
  const float* w2    = (const float*)d_in[10];
  const float* b2    = (const float*)d_in[11];
  float* h = (float*)d_out;

  char* ws = (char*)d_ws;
  short* wqkv_t  = (short*)ws; ws += (size_t)DEPTHL * QKVN * CDIM * 2;
  short* wproj_t = (short*)ws; ws += (size_t)DEPTHL * CDIM * CDIM * 2;
  short* w1_t    = (short*)ws; ws += (size_t)DEPTHL * MLPD * CDIM * 2;
  short* w2_t    = (short*)ws; ws += (size_t)DEPTHL * CDIM * MLPD * 2;
  short* ybf     = (short*)ws; ws += (size_t)TOK * CDIM * 2;
  short* qkvbf   = (short*)ws; ws += (size_t)TOK * QKVN * 2;
  short* obf     = (short*)ws; ws += (size_t)TOK * CDIM * 2;
  short* f1bf    = (short*)ws; ws += (size_t)TOK * MLPD * 2;
  short* vtb     = f1bf;   // overlay: vt lifetime disjoint from f1

  hipMemcpyAsync(h, x, (size_t)TOK * CDIM * sizeof(float), hipMemcpyDeviceToDevice, stream);

  wconv_t<<<dim3(QKVN / 32, CDIM / 32, DEPTHL), 256, 0, stream>>>(wqkv, wqkv_t, CDIM, QKVN);
  wconv_t<<<dim3(CDIM / 32, CDIM / 32, DEPTHL), 256, 0, stream>>>(wproj, wproj_t, CDIM, CDIM);
  wconv_t<<<dim3(MLPD / 32, CDIM / 32, DEPTHL), 256, 0, stream>>>(w1, w1_t, CDIM, MLPD);
  wconv_t<<<dim3(CDIM / 32, MLPD / 32, DEPTHL), 256, 0, stream>>>(w2, w2_t, MLPD, CDIM);

  for (int l = 0; l < DEPTHL; l++) {
    ln_fwd<<<TOK / 4, 256, 0, stream>>>(h, ln1_g + l * CDIM, ln1_b + l * CDIM, ybf);
    gemm_bt<0><<<dim3(QKVN / 128, TOK / 128), 256, 0, stream>>>(
        ybf, wqkv_t + (size_t)l * QKVN * CDIM, nullptr, qkvbf, TOK, QKVN, CDIM);
    vtrans<<<dim3(SEQ / 32, HDIM / 32, BZ * HEADS), 256, 0, stream>>>(qkvbf, vtb);
    attn_fused7<<<dim3(SEQ / 32, BZ * HEADS), 256, 0, stream>>>(qkvbf, vtb, obf);
    gemm_bt<2><<<dim3(CDIM / 128, TOK / 128), 256, 0, stream>>>(
        obf, wproj_t + (size_t)l * CDIM * CDIM, bproj + l * CDIM, h, TOK, CDIM, CDIM);
    ln_fwd<<<TOK / 4, 256, 0, stream>>>(h, ln2_g + l * CDIM, ln2_b + l * CDIM, ybf);
    gemm_bt<1><<<dim3(MLPD / 128, TOK / 128), 256, 0, stream>>>(
        ybf, w1_t + (size_t)l * MLPD * CDIM, b1 + l * MLPD, f1bf, TOK, MLPD, CDIM);
    gemm_bt<2><<<dim3(CDIM / 128, TOK / 128), 256, 0, stream>>>(
        f1bf, w2_t + (size_t)l * CDIM * MLPD, b2 + l * CDIM, h, TOK, CDIM, MLPD);
  }
}